// Round 12
// baseline (582.959 us; speedup 1.0000x reference)
//
#include <hip/hip_runtime.h>
#include <hip/hip_bf16.h>

#define BB 128
#define SS 32
#define NSTEP 31
#define IND 32
#define HID 128
#define HID2 256

typedef unsigned short u16;
typedef unsigned int u32;
typedef _Float16 f16;
typedef f16 h2 __attribute__((ext_vector_type(2)));
typedef __fp16 fp16v2 __attribute__((ext_vector_type(2)));
typedef _Float16 f16x8 __attribute__((ext_vector_type(8)));
typedef float f32x4 __attribute__((ext_vector_type(4)));

__device__ __forceinline__ u32 pkh2(float a, float b){
  fp16v2 r = __builtin_amdgcn_cvt_pkrtz(a, b);
  u32 u; __builtin_memcpy(&u, &r, 4); return u;
}
__device__ __forceinline__ u16 f2h(float f){ f16 h = (f16)f; u16 u; __builtin_memcpy(&u, &h, 2); return u; }
__device__ __forceinline__ float gelu_f(float x){ return 0.5f * x * (1.0f + erff(x * 0.70710678118654752440f)); }
__device__ __forceinline__ void setprio_hi(){
#if __has_builtin(__builtin_amdgcn_s_setprio)
  __builtin_amdgcn_s_setprio(3);
#endif
}
__device__ __forceinline__ void setprio_lo(){
#if __has_builtin(__builtin_amdgcn_s_setprio)
  __builtin_amdgcn_s_setprio(0);
#endif
}

// DPP wave64 sum -> valid in lane 63
__device__ __forceinline__ float wred(float v){
  int iv; float tf;
  #define DPPADD(CTRL, RMASK) \
    __builtin_memcpy(&iv, &v, 4); \
    iv = __builtin_amdgcn_update_dpp(0, iv, CTRL, RMASK, 0xf, true); \
    __builtin_memcpy(&tf, &iv, 4); \
    v += tf;
  DPPADD(0x111, 0xf)
  DPPADD(0x112, 0xf)
  DPPADD(0x114, 0xf)
  DPPADD(0x118, 0xf)
  DPPADD(0x142, 0xa)
  DPPADD(0x143, 0xc)
  #undef DPPADD
  return v;
}

// block-wide sum of (x,y) over 256 threads — enc/epi only
__device__ __forceinline__ void bsum2(float x, float y, float* red, int tid, float& ox, float& oy){
  #pragma unroll
  for (int off = 32; off >= 1; off >>= 1){ x += __shfl_xor(x, off); y += __shfl_xor(y, off); }
  __syncthreads();
  if ((tid & 63) == 0){ red[(tid >> 6)*2] = x; red[(tid >> 6)*2 + 1] = y; }
  __syncthreads();
  ox = red[0] + red[2] + red[4] + red[6];
  oy = red[1] + red[3] + red[5] + red[7];
}

// ---------------- merged setup: prep_misc / pack w3f (MFMA B-frags) / pack_wf ----------------
// w3f layout: [h(128)][kt(8)][eo(2)][lane(64)][j(4)] u32
//   n=lane&15, quad=lane>>4; krow = kt*32 + (n>>2)*8 + 2*(n&3) + eo
//   u32 j packs W3[krow][h*32 + quad*8 + 2j], W3[krow][h*32 + quad*8 + 2j+1]
__global__ __launch_bounds__(256) void setup_kernel(const float* __restrict__ path,
                                                    const float* __restrict__ ts,
                                                    const float* __restrict__ b3,
                                                    const float* __restrict__ W3,
                                                    const float* __restrict__ W1,
                                                    const float* __restrict__ W2,
                                                    u32* __restrict__ dxh,
                                                    float* __restrict__ hb,
                                                    float* __restrict__ gb,
                                                    u32* __restrict__ w3f,
                                                    u32* __restrict__ w1f,
                                                    u32* __restrict__ w2f){
  const int blk = blockIdx.x, tid = threadIdx.x;
  if (blk < BB){
    const int b = blk;
    __shared__ float sdxp[NSTEP * IND];
    for (int t = tid; t < NSTEP * IND; t += 256){
      int s = t >> 5, i = t & 31;
      float dt = ts[b*SS + s + 1] - ts[b*SS + s];
      sdxp[t] = (path[(b*SS + s + 1)*IND + i] - path[(b*SS + s)*IND + i]) / dt;
    }
    if (tid < NSTEP) hb[b*NSTEP + tid] = ts[b*SS + tid + 1] - ts[b*SS + tid];
    __syncthreads();
    for (int t = tid; t < NSTEP * 16; t += 256){
      int s = t >> 4, i2 = t & 15;
      dxh[((size_t)b*NSTEP + s)*16 + i2] = pkh2(sdxp[s*IND + 2*i2], sdxp[s*IND + 2*i2 + 1]);
    }
    if (tid < HID){
      float w[IND];
      #pragma unroll
      for (int i = 0; i < IND; ++i) w[i] = b3[tid*IND + i];
      for (int s = 0; s < NSTEP; ++s){
        float a = 0.f;
        #pragma unroll
        for (int i = 0; i < IND; ++i) a = fmaf(w[i], sdxp[s*IND + i], a);
        gb[(b*NSTEP + s)*HID + tid] = a;
      }
    }
  } else if (blk < BB + 2048){
    int i = (blk - BB)*256 + tid;            // 524288 u32 of w3f
    int j = i & 3, lane = (i >> 2) & 63, eo = (i >> 8) & 1, kt = (i >> 9) & 7, h = i >> 12;
    int n = lane & 15, quad = lane >> 4;
    int krow = kt*32 + (n >> 2)*8 + 2*(n & 3) + eo;
    int i0 = quad*8 + 2*j;
    const float* wr = W3 + (size_t)krow*4096 + h*IND;
    w3f[i] = pkh2(wr[i0], wr[i0 + 1]);
  } else {
    int i = (blk - BB - 2048)*256 + tid;
    if (i < 16384){
      int lane_blk = i >> 6, rem = i & 63;
      int i16 = rem >> 2, q = rem & 3;
      int w = lane_blk >> 6, lane = lane_blk & 63;
      int kt = i16 >> 2, nt = i16 & 3;
      int k = kt*32 + (lane >> 4)*8 + 2*q;
      int col = w*64 + nt*16 + (lane & 15);
      w1f[i] = pkh2(W1[(size_t)k*HID2 + col], W1[(size_t)(k+1)*HID2 + col]);
    } else if (i < 16384 + 32768){
      int j = i - 16384;
      int lane_blk = j >> 7, rem = j & 127;
      int i32i = rem >> 2, q = rem & 3;
      int w = lane_blk >> 6, lane = lane_blk & 63;
      int kt = i32i >> 2, nt = i32i & 3;
      int k = kt*32 + (lane >> 4)*8 + 2*q;
      int col = w*64 + nt*16 + (lane & 15);
      w2f[j] = pkh2(W2[(size_t)k*HID2 + col], W2[(size_t)(k+1)*HID2 + col]);
    }
  }
}

// ---------------- fused scan + MFMA G-prep ----------------
struct FusedP {
  const float *path;
  const float *eW1,*eb1,*eg1,*ebt1,*eW2,*eb2,*eg2,*ebt2;
  const u32 *w1f, *w2f;
  const float *b1,*g1,*bt1,*b2,*g2,*bt2;
  const float *Wv,*bv,*Wo,*bo,*dW1,*db1,*dW2,*db2;
  const float *hb,*gb;
  const u32 *Gp;          // scan-consumed buffer
  float *zstate, *out;
  int s0, s1, do_enc, do_epi, scan_on;
  const u32 *w3f, *dxh;
  u32 *Gpw;               // prep-written buffer
  int ps0, pcs;
};

__global__ __launch_bounds__(256, 1) void fused_kernel(FusedP p){
  const int tid = threadIdx.x;
  // scan shared
  __shared__ __align__(16) u16 zst_h[HID];
  __shared__ __align__(16) u16 a1p_h[HID2];
  __shared__ __align__(16) u16 a2p_h[HID2];
  __shared__ __align__(16) float red[8];
  __shared__ __align__(16) float zf[HID];
  __shared__ __align__(16) float sc1[HID2];
  // prep shared
  __shared__ __align__(16) u32 sdx[BB * 16];

  if (p.scan_on && blockIdx.x < BB){
    // ================= SCAN (unchanged verified body) =================
    setprio_hi();
    const int b = blockIdx.x;
    const int lane = tid & 63, w = tid >> 6;
    const int quad = lane >> 4, n16 = lane & 15;
    const bool owner = (quad == 0);

    uint4 w1r[16], w2r[32];
    {
      const uint4* s1p = (const uint4*)p.w1f + ((size_t)(w*64 + lane))*16;
      #pragma unroll
      for (int i = 0; i < 16; ++i) w1r[i] = s1p[i];
      const uint4* s2p = (const uint4*)p.w2f + ((size_t)(w*64 + lane))*32;
      #pragma unroll
      for (int i = 0; i < 32; ++i) w2r[i] = s2p[i];
    }
    float rb1[4], rg1[4], rbt1[4], rb2[4], rg2[4], rbt2[4];
    #pragma unroll
    for (int nt = 0; nt < 4; ++nt){
      int col = w*64 + nt*16 + n16;
      rb1[nt] = p.b1[col]; rg1[nt] = p.g1[col]; rbt1[nt] = p.bt1[col];
      rb2[nt] = p.b2[col]; rg2[nt] = p.g2[col]; rbt2[nt] = p.bt2[col];
    }
    const int h0 = w*32 + n16, h1 = h0 + 16;

    float mu, sq;
    if (p.do_enc){
      if (tid < IND) sc1[tid] = p.path[(b*SS + 0)*IND + tid];
      __syncthreads();
      float acc = 0.f;
      if (tid < HID){
        acc = p.eb1[tid];
        #pragma unroll 8
        for (int i = 0; i < IND; ++i) acc = fmaf(sc1[i], p.eW1[i*HID + tid], acc);
      }
      float cx = (tid < HID) ? acc : 0.f;
      bsum2(cx, cx*cx, red, tid, mu, sq);
      mu *= (1.f/HID); float var = sq*(1.f/HID) - mu*mu; float rstd = rsqrtf(var + 1e-5f);
      if (tid < HID) zf[tid] = gelu_f((acc - mu)*rstd*p.eg1[tid] + p.ebt1[tid]);
      __syncthreads();
      float acc2 = 0.f;
      if (tid < HID){
        acc2 = p.eb2[tid];
        #pragma unroll 8
        for (int h = 0; h < HID; ++h) acc2 = fmaf(zf[h], p.eW2[h*HID + tid], acc2);
      }
      cx = (tid < HID) ? acc2 : 0.f;
      bsum2(cx, cx*cx, red, tid, mu, sq);
      mu *= (1.f/HID); float var2 = sq*(1.f/HID) - mu*mu; float rstd2 = rsqrtf(var2 + 1e-5f);
      __syncthreads();
      if (tid < HID) zf[tid] = (acc2 - mu)*rstd2*p.eg2[tid] + p.ebt2[tid];
      __syncthreads();
    }
    float zc0 = 0.f, zc1 = 0.f;
    if (owner){
      if (p.do_enc){ zc0 = zf[h0]; zc1 = zf[h1]; }
      else { zc0 = p.zstate[b*HID + h0]; zc1 = p.zstate[b*HID + h1]; }
    }

    for (int s = p.s0; s < p.s1; ++s){
      const float hbv = p.hb[b*NSTEP + s];
      uint4 gr[16];
      {
        const uint4* g4 = (const uint4*)(p.Gp + ((size_t)(s - p.s0)*BB + b)*16384 + (size_t)w*4096);
        #pragma unroll
        for (int m = 0; m < 16; ++m) gr[m] = g4[m*64 + lane];
      }
      float gb0 = 0.f, gb1 = 0.f;
      if (owner){
        gb0 = p.gb[(b*NSTEP + s)*HID + h0];
        gb1 = p.gb[(b*NSTEP + s)*HID + h1];
        zst_h[h0] = f2h(zc0); zst_h[h1] = f2h(zc1);
      }
      float ks0 = 0.f, ks1 = 0.f;
      __syncthreads();

      #pragma unroll 1
      for (int st = 0; st < 4; ++st){
        // layer1
        f32x4 D0a={0,0,0,0}, D1a={0,0,0,0}, D2a={0,0,0,0}, D3a={0,0,0,0};
        f32x4 D0b={0,0,0,0}, D1b={0,0,0,0}, D2b={0,0,0,0}, D3b={0,0,0,0};
        {
          const uint4* za = (const uint4*)zst_h;
          #pragma unroll
          for (int kt = 0; kt < 2; ++kt){
            f16x8 a; uint4 av = za[kt*4 + quad]; __builtin_memcpy(&a, &av, 16);
            f16x8 bf;
            __builtin_memcpy(&bf, &w1r[kt*4+0], 16); D0a = __builtin_amdgcn_mfma_f32_16x16x32_f16(a, bf, D0a, 0, 0, 0);
            __builtin_memcpy(&bf, &w1r[kt*4+1], 16); D1a = __builtin_amdgcn_mfma_f32_16x16x32_f16(a, bf, D1a, 0, 0, 0);
            __builtin_memcpy(&bf, &w1r[kt*4+2], 16); D2a = __builtin_amdgcn_mfma_f32_16x16x32_f16(a, bf, D2a, 0, 0, 0);
            __builtin_memcpy(&bf, &w1r[kt*4+3], 16); D3a = __builtin_amdgcn_mfma_f32_16x16x32_f16(a, bf, D3a, 0, 0, 0);
          }
          #pragma unroll
          for (int kt = 2; kt < 4; ++kt){
            f16x8 a; uint4 av = za[kt*4 + quad]; __builtin_memcpy(&a, &av, 16);
            f16x8 bf;
            __builtin_memcpy(&bf, &w1r[kt*4+0], 16); D0b = __builtin_amdgcn_mfma_f32_16x16x32_f16(a, bf, D0b, 0, 0, 0);
            __builtin_memcpy(&bf, &w1r[kt*4+1], 16); D1b = __builtin_amdgcn_mfma_f32_16x16x32_f16(a, bf, D1b, 0, 0, 0);
            __builtin_memcpy(&bf, &w1r[kt*4+2], 16); D2b = __builtin_amdgcn_mfma_f32_16x16x32_f16(a, bf, D2b, 0, 0, 0);
            __builtin_memcpy(&bf, &w1r[kt*4+3], 16); D3b = __builtin_amdgcn_mfma_f32_16x16x32_f16(a, bf, D3b, 0, 0, 0);
          }
        }
        float v0 = (D0a[0]+D0b[0]) + rb1[0], v1 = (D1a[0]+D1b[0]) + rb1[1];
        float v2 = (D2a[0]+D2b[0]) + rb1[2], v3 = (D3a[0]+D3b[0]) + rb1[3];
        float ssum = wred((v0 + v1) + (v2 + v3));
        float ssq  = wred((v0*v0 + v1*v1) + (v2*v2 + v3*v3));
        if (lane == 63){ red[w*2] = ssum; red[w*2+1] = ssq; }
        __syncthreads();                                    // b1
        {
          const float4* r4 = (const float4*)red;
          float4 ra = r4[0], rb = r4[1];
          float m1 = (ra.x + ra.z + rb.x + rb.z)*(1.f/1024.f);
          float q1 = (ra.y + ra.w + rb.y + rb.w)*(1.f/1024.f);
          float rs1 = rsqrtf(q1 - m1*m1 + 1e-5f);
          if (owner){
            a1p_h[w*64 +  0 + n16] = f2h(gelu_f((v0 - m1)*rs1*rg1[0] + rbt1[0]));
            a1p_h[w*64 + 16 + n16] = f2h(gelu_f((v1 - m1)*rs1*rg1[1] + rbt1[1]));
            a1p_h[w*64 + 32 + n16] = f2h(gelu_f((v2 - m1)*rs1*rg1[2] + rbt1[2]));
            a1p_h[w*64 + 48 + n16] = f2h(gelu_f((v3 - m1)*rs1*rg1[3] + rbt1[3]));
          }
        }
        __syncthreads();                                    // b2
        // layer2
        D0a={0,0,0,0}; D1a={0,0,0,0}; D2a={0,0,0,0}; D3a={0,0,0,0};
        D0b={0,0,0,0}; D1b={0,0,0,0}; D2b={0,0,0,0}; D3b={0,0,0,0};
        {
          const uint4* aa = (const uint4*)a1p_h;
          #pragma unroll
          for (int kt = 0; kt < 4; ++kt){
            f16x8 a; uint4 av = aa[kt*4 + quad]; __builtin_memcpy(&a, &av, 16);
            f16x8 bf;
            __builtin_memcpy(&bf, &w2r[kt*4+0], 16); D0a = __builtin_amdgcn_mfma_f32_16x16x32_f16(a, bf, D0a, 0, 0, 0);
            __builtin_memcpy(&bf, &w2r[kt*4+1], 16); D1a = __builtin_amdgcn_mfma_f32_16x16x32_f16(a, bf, D1a, 0, 0, 0);
            __builtin_memcpy(&bf, &w2r[kt*4+2], 16); D2a = __builtin_amdgcn_mfma_f32_16x16x32_f16(a, bf, D2a, 0, 0, 0);
            __builtin_memcpy(&bf, &w2r[kt*4+3], 16); D3a = __builtin_amdgcn_mfma_f32_16x16x32_f16(a, bf, D3a, 0, 0, 0);
          }
          #pragma unroll
          for (int kt = 4; kt < 8; ++kt){
            f16x8 a; uint4 av = aa[kt*4 + quad]; __builtin_memcpy(&a, &av, 16);
            f16x8 bf;
            __builtin_memcpy(&bf, &w2r[kt*4+0], 16); D0b = __builtin_amdgcn_mfma_f32_16x16x32_f16(a, bf, D0b, 0, 0, 0);
            __builtin_memcpy(&bf, &w2r[kt*4+1], 16); D1b = __builtin_amdgcn_mfma_f32_16x16x32_f16(a, bf, D1b, 0, 0, 0);
            __builtin_memcpy(&bf, &w2r[kt*4+2], 16); D2b = __builtin_amdgcn_mfma_f32_16x16x32_f16(a, bf, D2b, 0, 0, 0);
            __builtin_memcpy(&bf, &w2r[kt*4+3], 16); D3b = __builtin_amdgcn_mfma_f32_16x16x32_f16(a, bf, D3b, 0, 0, 0);
          }
        }
        v0 = (D0a[0]+D0b[0]) + rb2[0]; v1 = (D1a[0]+D1b[0]) + rb2[1];
        v2 = (D2a[0]+D2b[0]) + rb2[2]; v3 = (D3a[0]+D3b[0]) + rb2[3];
        ssum = wred((v0 + v1) + (v2 + v3));
        ssq  = wred((v0*v0 + v1*v1) + (v2*v2 + v3*v3));
        if (lane == 63){ red[w*2] = ssum; red[w*2+1] = ssq; }
        __syncthreads();                                    // b3
        {
          const float4* r4 = (const float4*)red;
          float4 ra = r4[0], rb = r4[1];
          float m2 = (ra.x + ra.z + rb.x + rb.z)*(1.f/1024.f);
          float q2 = (ra.y + ra.w + rb.y + rb.w)*(1.f/1024.f);
          float rs2 = rsqrtf(q2 - m2*m2 + 1e-5f);
          if (owner){
            a2p_h[w*64 +  0 + n16] = f2h(gelu_f((v0 - m2)*rs2*rg2[0] + rbt2[0]));
            a2p_h[w*64 + 16 + n16] = f2h(gelu_f((v1 - m2)*rs2*rg2[1] + rbt2[1]));
            a2p_h[w*64 + 32 + n16] = f2h(gelu_f((v2 - m2)*rs2*rg2[2] + rbt2[2]));
            a2p_h[w*64 + 48 + n16] = f2h(gelu_f((v3 - m2)*rs2*rg2[3] + rbt2[3]));
          }
        }
        __syncthreads();                                    // b4
        // layer3
        f32x4 E0={0,0,0,0}, E1={0,0,0,0}, E2={0,0,0,0}, E3={0,0,0,0};
        {
          const uint4* aa = (const uint4*)a2p_h;
          #pragma unroll
          for (int kt = 0; kt < 4; ++kt){
            f16x8 a; uint4 av = aa[kt*4 + quad]; __builtin_memcpy(&a, &av, 16);
            f16x8 g0f, g1f;
            __builtin_memcpy(&g0f, &gr[kt*2+0], 16);
            __builtin_memcpy(&g1f, &gr[kt*2+1], 16);
            E0 = __builtin_amdgcn_mfma_f32_16x16x32_f16(a, g0f, E0, 0, 0, 0);
            E1 = __builtin_amdgcn_mfma_f32_16x16x32_f16(a, g1f, E1, 0, 0, 0);
          }
          #pragma unroll
          for (int kt = 4; kt < 8; ++kt){
            f16x8 a; uint4 av = aa[kt*4 + quad]; __builtin_memcpy(&a, &av, 16);
            f16x8 g0f, g1f;
            __builtin_memcpy(&g0f, &gr[kt*2+0], 16);
            __builtin_memcpy(&g1f, &gr[kt*2+1], 16);
            E2 = __builtin_amdgcn_mfma_f32_16x16x32_f16(a, g0f, E2, 0, 0, 0);
            E3 = __builtin_amdgcn_mfma_f32_16x16x32_f16(a, g1f, E3, 0, 0, 0);
          }
        }
        if (owner){
          float kv0 = (E0[0] + E2[0]) + gb0, kv1 = (E1[0] + E3[0]) + gb1;
          float cst = (st == 0 || st == 3) ? 1.f : 2.f;
          ks0 += cst*kv0; ks1 += cst*kv1;
          if (st < 3){
            float c = (st == 2) ? hbv : 0.5f*hbv;
            zst_h[h0] = f2h(zc0 + c*kv0);
            zst_h[h1] = f2h(zc1 + c*kv1);
          }
        }
        __syncthreads();                                    // b5
      }
      if (owner){ zc0 += hbv*(1.f/6.f)*ks0; zc1 += hbv*(1.f/6.f)*ks1; }
    }

    if (p.do_epi){
      if (owner){ zf[h0] = zc0; zf[h1] = zc1; }
      __syncthreads();
      if (tid < HID){
        float v = p.bv[tid];
        #pragma unroll 8
        for (int h = 0; h < HID; ++h) v = fmaf(zf[h], p.Wv[h*HID + tid], v);
        sc1[tid] = v;
      }
      __syncthreads();
      if (tid < HID){
        float f = p.bo[tid];
        #pragma unroll 8
        for (int h = 0; h < HID; ++h) f = fmaf(sc1[h], p.Wo[h*HID + tid], f);
        sc1[HID + tid] = f;
      }
      __syncthreads();
      if (tid < HID){
        float hd = p.db1[tid];
        #pragma unroll 8
        for (int h = 0; h < HID; ++h) hd = fmaf(sc1[HID + h], p.dW1[h*HID + tid], hd);
        zf[tid] = gelu_f(hd);
      }
      __syncthreads();
      if (tid < 10){
        float t = p.db2[tid];
        #pragma unroll 8
        for (int h = 0; h < HID; ++h) t = fmaf(zf[h], p.dW2[h*10 + tid], t);
        p.out[b*10 + tid] = t;
      }
      if (tid == 0) p.out[BB*10 + b] = 1.0f;   // softmax over singleton axis == 1
    } else {
      if (owner){ p.zstate[b*HID + h0] = zc0; p.zstate[b*HID + h1] = zc1; }
    }
    return;
  }

  // ================= MFMA G-PREP: 8 blocks per step-slice =================
  {
    setprio_lo();
    const int pb = blockIdx.x - (p.scan_on ? BB : 0);
    const int sl = pb >> 3, xblk = pb & 7;
    if (sl >= p.pcs) return;
    const int s = p.ps0 + sl;
    const int lane = tid & 63, w = tid >> 6;
    const int quad = lane >> 4, n16 = lane & 15;

    // stage dx (packed half2) for all 128 batches of this step
    for (int t = tid; t < BB * 16; t += 256){
      int bb = t >> 4, i2 = t & 15;
      sdx[t] = p.dxh[((size_t)bb*NSTEP + s)*16 + i2];
    }
    __syncthreads();

    // A-fragments: a[mt] = dx rows b = mt*16 + n16, i = quad*8..+8
    uint4 arf[8];
    {
      const uint4* sdx4 = (const uint4*)sdx;
      #pragma unroll
      for (int mt = 0; mt < 8; ++mt) arf[mt] = sdx4[(mt*16 + n16)*4 + quad];
    }

    u32* __restrict__ Gout = p.Gpw + (size_t)sl * BB * 16384;
    const int noff = ((n16 >> 2)*64) + (n16 & 3);
    const int h0 = xblk*16 + w*4;

    #pragma unroll 1
    for (int hh = 0; hh < 4; ++hh){
      const int h = h0 + hh;
      const int hkt_base = (h >> 5)*4096 + ((h >> 4) & 1)*256 + (h & 15)*4;
      const uint4* wb4 = (const uint4*)p.w3f + ((size_t)(h*8))*128;   // per (h): 8 kt × 2 eo × 64 uint4
      #pragma unroll 1
      for (int kt = 0; kt < 8; ++kt){
        f16x8 Be, Bo;
        {
          uint4 be = wb4[(kt*2 + 0)*64 + lane];
          uint4 bo = wb4[(kt*2 + 1)*64 + lane];
          __builtin_memcpy(&Be, &be, 16);
          __builtin_memcpy(&Bo, &bo, 16);
        }
        const int hkt = hkt_base + kt*512;     // (kt*2+tq)*256 with tq folded in base
        #pragma unroll
        for (int mt = 0; mt < 8; ++mt){
          f16x8 a; __builtin_memcpy(&a, &arf[mt], 16);
          f32x4 De = __builtin_amdgcn_mfma_f32_16x16x32_f16(a, Be, (f32x4){0,0,0,0}, 0, 0, 0);
          f32x4 Do = __builtin_amdgcn_mfma_f32_16x16x32_f16(a, Bo, (f32x4){0,0,0,0}, 0, 0, 0);
          const int bbase = mt*16 + quad*4;
          #pragma unroll
          for (int r = 0; r < 4; ++r){
            Gout[(size_t)(bbase + r)*16384 + hkt + noff] = pkh2(De[r], Do[r]);
          }
        }
      }
    }
  }
}

extern "C" void kernel_launch(void* const* d_in, const int* in_sizes, int n_in,
                              void* d_out, int out_size, void* d_ws, size_t ws_size,
                              hipStream_t stream){
  const float* path  = (const float*)d_in[0];
  const float* ts    = (const float*)d_in[1];
  const float* eW1   = (const float*)d_in[2];
  const float* eb1   = (const float*)d_in[3];
  const float* eg1   = (const float*)d_in[4];
  const float* ebt1  = (const float*)d_in[5];
  const float* eW2   = (const float*)d_in[6];
  const float* eb2   = (const float*)d_in[7];
  const float* eg2   = (const float*)d_in[8];
  const float* ebt2  = (const float*)d_in[9];
  const float* vW1   = (const float*)d_in[10];
  const float* vb1   = (const float*)d_in[11];
  const float* vg1   = (const float*)d_in[12];
  const float* vbt1  = (const float*)d_in[13];
  const float* vW2   = (const float*)d_in[14];
  const float* vb2   = (const float*)d_in[15];
  const float* vg2   = (const float*)d_in[16];
  const float* vbt2  = (const float*)d_in[17];
  const float* vW3   = (const float*)d_in[18];
  const float* vb3   = (const float*)d_in[19];
  const float* Wv    = (const float*)d_in[24];
  const float* bv    = (const float*)d_in[25];
  const float* Wo    = (const float*)d_in[26];
  const float* bo    = (const float*)d_in[27];
  const float* dW1   = (const float*)d_in[28];
  const float* db1   = (const float*)d_in[29];
  const float* dW2   = (const float*)d_in[30];
  const float* db2   = (const float*)d_in[31];

  char* wsb = (char*)d_ws;
  float* z_state = (float*)(wsb + 0);              // 64 KB
  u32*   dxh = (u32*)(wsb + 65536);                // 248 KB
  float* hb  = (float*)(wsb + 319488);             // 16 KB
  float* gb  = (float*)(wsb + 335872);             // 1.94 MB
  u32*   w3f = (u32*)(wsb + 2367488);              // 2 MB (MFMA B-frags of W3)
  u32*   w1f = (u32*)(wsb + 4464640);              // 64 KB
  u32*   w2f = (u32*)(wsb + 4530176);              // 128 KB
  const size_t gbase = 4661248;

  hipLaunchKernelGGL(setup_kernel, dim3(BB + 2048 + 192), dim3(256), 0, stream,
                     path, ts, vb3, vW3, vW1, vW2, dxh, hb, gb, w3f, w1f, w2f);

  const size_t per_step = (size_t)BB * 16384 * 4;  // 8 MB per step
  size_t avail = (ws_size > gbase) ? (ws_size - gbase) : 0;
  int cap = (int)((avail/2) / per_step);           // max chunk with double buffer

  FusedP base;
  base.path = path;
  base.eW1 = eW1; base.eb1 = eb1; base.eg1 = eg1; base.ebt1 = ebt1;
  base.eW2 = eW2; base.eb2 = eb2; base.eg2 = eg2; base.ebt2 = ebt2;
  base.w1f = w1f; base.w2f = w2f;
  base.b1 = vb1; base.g1 = vg1; base.bt1 = vbt1;
  base.b2 = vb2; base.g2 = vg2; base.bt2 = vbt2;
  base.Wv = Wv; base.bv = bv; base.Wo = Wo; base.bo = bo;
  base.dW1 = dW1; base.db1 = db1; base.dW2 = dW2; base.db2 = db2;
  base.hb = hb; base.gb = gb;
  base.zstate = z_state; base.out = (float*)d_out;
  base.w3f = w3f; base.dxh = dxh;
  base.s0 = 0; base.s1 = 0; base.do_enc = 0; base.do_epi = 0; base.scan_on = 0;
  base.ps0 = 0; base.pcs = 0;

  if (cap >= 2){
    int c = cap < 8 ? cap : 8;
    if (c > NSTEP) c = NSTEP;
    const int nch = (NSTEP + c - 1) / c;
    u32* GpA = (u32*)(wsb + gbase);
    u32* GpB = (u32*)(wsb + gbase + (size_t)c*per_step);
    for (int i = 0; i <= nch; ++i){
      FusedP P = base;
      int scan_i = i - 1, prep_i = i;
      P.scan_on = (scan_i >= 0) ? 1 : 0;
      if (P.scan_on){
        P.s0 = scan_i*c;
        P.s1 = (P.s0 + c < NSTEP) ? (P.s0 + c) : NSTEP;
        P.Gp = (scan_i & 1) ? GpB : GpA;
        P.do_enc = (scan_i == 0) ? 1 : 0;
        P.do_epi = (P.s1 == NSTEP) ? 1 : 0;
      } else {
        P.Gp = GpA;
      }
      if (prep_i < nch){
        P.ps0 = prep_i*c;
        P.pcs = (NSTEP - P.ps0 < c) ? (NSTEP - P.ps0) : c;
        P.Gpw = (prep_i & 1) ? GpB : GpA;
      } else {
        P.pcs = 0; P.Gpw = GpA;
      }
      int grid = (P.scan_on ? BB : 0) + 8*P.pcs;
      if (grid == 0) continue;
      hipLaunchKernelGGL(fused_kernel, dim3(grid), dim3(256), 0, stream, P);
    }
  } else {
    int c = (int)(avail / per_step);
    if (c < 1) c = 1;
    if (c > NSTEP) c = NSTEP;
    u32* GpA = (u32*)(wsb + gbase);
    const int nch = (NSTEP + c - 1) / c;
    for (int i = 0; i < nch; ++i){
      int s0 = i*c;
      int cs = (NSTEP - s0 < c) ? (NSTEP - s0) : c;
      FusedP P1 = base;                 // prep only
      P1.scan_on = 0; P1.ps0 = s0; P1.pcs = cs; P1.Gpw = GpA; P1.Gp = GpA;
      hipLaunchKernelGGL(fused_kernel, dim3(8*cs), dim3(256), 0, stream, P1);
      FusedP P2 = base;                 // scan only
      P2.scan_on = 1; P2.pcs = 0; P2.Gpw = GpA;
      P2.s0 = s0; P2.s1 = s0 + cs; P2.Gp = GpA;
      P2.do_enc = (s0 == 0) ? 1 : 0;
      P2.do_epi = (s0 + cs == NSTEP) ? 1 : 0;
      hipLaunchKernelGGL(fused_kernel, dim3(BB), dim3(256), 0, stream, P2);
    }
  }
}

// Round 13
// 549.046 us; speedup vs baseline: 1.0618x; 1.0618x over previous
//
#include <hip/hip_runtime.h>
#include <hip/hip_bf16.h>

#define BB 128
#define SS 32
#define NSTEP 31
#define IND 32
#define HID 128
#define HID2 256

typedef unsigned short u16;
typedef unsigned int u32;
typedef _Float16 f16;
typedef f16 h2 __attribute__((ext_vector_type(2)));
typedef __fp16 fp16v2 __attribute__((ext_vector_type(2)));
typedef _Float16 f16x8 __attribute__((ext_vector_type(8)));
typedef float f32x4 __attribute__((ext_vector_type(4)));

__device__ __forceinline__ float dot2f(u32 a, u32 b, float c){
#if __has_builtin(__builtin_amdgcn_fdot2)
  h2 ha, hb; __builtin_memcpy(&ha, &a, 4); __builtin_memcpy(&hb, &b, 4);
  return __builtin_amdgcn_fdot2(ha, hb, c, false);
#else
  h2 ha, hb; __builtin_memcpy(&ha, &a, 4); __builtin_memcpy(&hb, &b, 4);
  return c + (float)ha[0]*(float)hb[0] + (float)ha[1]*(float)hb[1];
#endif
}
__device__ __forceinline__ u32 pkh2(float a, float b){
  fp16v2 r = __builtin_amdgcn_cvt_pkrtz(a, b);
  u32 u; __builtin_memcpy(&u, &r, 4); return u;
}
__device__ __forceinline__ u16 f2h(float f){ f16 h = (f16)f; u16 u; __builtin_memcpy(&u, &h, 2); return u; }
__device__ __forceinline__ float gelu_f(float x){ return 0.5f * x * (1.0f + erff(x * 0.70710678118654752440f)); }
__device__ __forceinline__ void setprio_hi(){
#if __has_builtin(__builtin_amdgcn_s_setprio)
  __builtin_amdgcn_s_setprio(3);
#endif
}
__device__ __forceinline__ void setprio_lo(){
#if __has_builtin(__builtin_amdgcn_s_setprio)
  __builtin_amdgcn_s_setprio(0);
#endif
}

// DPP wave64 sum -> valid in lane 63
__device__ __forceinline__ float wred(float v){
  int iv; float tf;
  #define DPPADD(CTRL, RMASK) \
    __builtin_memcpy(&iv, &v, 4); \
    iv = __builtin_amdgcn_update_dpp(0, iv, CTRL, RMASK, 0xf, true); \
    __builtin_memcpy(&tf, &iv, 4); \
    v += tf;
  DPPADD(0x111, 0xf)
  DPPADD(0x112, 0xf)
  DPPADD(0x114, 0xf)
  DPPADD(0x118, 0xf)
  DPPADD(0x142, 0xa)
  DPPADD(0x143, 0xc)
  #undef DPPADD
  return v;
}

// block-wide sum of (x,y) over 256 threads — enc/epi only
__device__ __forceinline__ void bsum2(float x, float y, float* red, int tid, float& ox, float& oy){
  #pragma unroll
  for (int off = 32; off >= 1; off >>= 1){ x += __shfl_xor(x, off); y += __shfl_xor(y, off); }
  __syncthreads();
  if ((tid & 63) == 0){ red[(tid >> 6)*2] = x; red[(tid >> 6)*2 + 1] = y; }
  __syncthreads();
  ox = red[0] + red[2] + red[4] + red[6];
  oy = red[1] + red[3] + red[5] + red[7];
}

// ---------------- merged setup: prep_misc / pack_w3 / pack_wf ----------------
__global__ __launch_bounds__(256) void setup_kernel(const float* __restrict__ path,
                                                    const float* __restrict__ ts,
                                                    const float* __restrict__ b3,
                                                    const float* __restrict__ W3,
                                                    const float* __restrict__ W1,
                                                    const float* __restrict__ W2,
                                                    u32* __restrict__ dxh,
                                                    float* __restrict__ hb,
                                                    float* __restrict__ gb,
                                                    u32* __restrict__ w3h,
                                                    u32* __restrict__ w1f,
                                                    u32* __restrict__ w2f){
  const int blk = blockIdx.x, tid = threadIdx.x;
  if (blk < BB){
    // ---- prep_misc for batch b = blk ----
    const int b = blk;
    __shared__ float sdxp[NSTEP * IND];
    for (int t = tid; t < NSTEP * IND; t += 256){
      int s = t >> 5, i = t & 31;
      float dt = ts[b*SS + s + 1] - ts[b*SS + s];
      sdxp[t] = (path[(b*SS + s + 1)*IND + i] - path[(b*SS + s)*IND + i]) / dt;
    }
    if (tid < NSTEP) hb[b*NSTEP + tid] = ts[b*SS + tid + 1] - ts[b*SS + tid];
    __syncthreads();
    for (int t = tid; t < NSTEP * 16; t += 256){
      int s = t >> 4, i2 = t & 15;
      dxh[((size_t)b*NSTEP + s)*16 + i2] = pkh2(sdxp[s*IND + 2*i2], sdxp[s*IND + 2*i2 + 1]);
    }
    if (tid < HID){
      float w[IND];
      #pragma unroll
      for (int i = 0; i < IND; ++i) w[i] = b3[tid*IND + i];
      for (int s = 0; s < NSTEP; ++s){
        float a = 0.f;
        #pragma unroll
        for (int i = 0; i < IND; ++i) a = fmaf(w[i], sdxp[s*IND + i], a);
        gb[(b*NSTEP + s)*HID + tid] = a;
      }
    }
  } else if (blk < BB + 2048){
    int i = (blk - BB)*256 + tid;
    if (i < (HID2*HID*IND)/2) w3h[i] = pkh2(W3[2*i], W3[2*i + 1]);
  } else {
    int i = (blk - BB - 2048)*256 + tid;
    if (i < 16384){
      int lane_blk = i >> 6, rem = i & 63;
      int i16 = rem >> 2, q = rem & 3;
      int w = lane_blk >> 6, lane = lane_blk & 63;
      int kt = i16 >> 2, nt = i16 & 3;
      int k = kt*32 + (lane >> 4)*8 + 2*q;
      int col = w*64 + nt*16 + (lane & 15);
      w1f[i] = pkh2(W1[(size_t)k*HID2 + col], W1[(size_t)(k+1)*HID2 + col]);
    } else if (i < 16384 + 32768){
      int j = i - 16384;
      int lane_blk = j >> 7, rem = j & 127;
      int i32i = rem >> 2, q = rem & 3;
      int w = lane_blk >> 6, lane = lane_blk & 63;
      int kt = i32i >> 2, nt = i32i & 3;
      int k = kt*32 + (lane >> 4)*8 + 2*q;
      int col = w*64 + nt*16 + (lane & 15);
      w2f[j] = pkh2(W2[(size_t)k*HID2 + col], W2[(size_t)(k+1)*HID2 + col]);
    }
  }
}

// ---------------- fused scan + G-prep ----------------
struct FusedP {
  // scan
  const float *path;
  const float *eW1,*eb1,*eg1,*ebt1,*eW2,*eb2,*eg2,*ebt2;
  const u32 *w1f, *w2f;
  const float *b1,*g1,*bt1,*b2,*g2,*bt2;
  const float *Wv,*bv,*Wo,*bo,*dW1,*db1,*dW2,*db2;
  const float *hb,*gb;
  const u32 *Gp;          // scan-consumed buffer
  float *zstate, *out;
  int s0, s1, do_enc, do_epi, scan_on;
  // prep
  const u32 *w3h, *dxh;
  u32 *Gpw;               // prep-written buffer
  int ps0, pcs;
};

__global__ __launch_bounds__(256, 1) void fused_kernel(FusedP p){
  const int tid = threadIdx.x;
  // scan shared
  __shared__ __align__(16) u16 zst_h[HID];
  __shared__ __align__(16) u16 a1p_h[HID2];
  __shared__ __align__(16) u16 a2p_h[HID2];
  __shared__ __align__(16) float red[8];
  __shared__ __align__(16) float zf[HID];
  __shared__ __align__(16) float sc1[HID2];
  // prep shared
  __shared__ u32 sdx[BB * 16];

  if (p.scan_on && blockIdx.x < BB){
    // ================= SCAN =================
    setprio_hi();
    const int b = blockIdx.x;
    const int lane = tid & 63, w = tid >> 6;
    const int quad = lane >> 4, n16 = lane & 15;
    const bool owner = (quad == 0);

    uint4 w1r[16], w2r[32];
    {
      const uint4* s1p = (const uint4*)p.w1f + ((size_t)(w*64 + lane))*16;
      #pragma unroll
      for (int i = 0; i < 16; ++i) w1r[i] = s1p[i];
      const uint4* s2p = (const uint4*)p.w2f + ((size_t)(w*64 + lane))*32;
      #pragma unroll
      for (int i = 0; i < 32; ++i) w2r[i] = s2p[i];
    }
    float rb1[4], rg1[4], rbt1[4], rb2[4], rg2[4], rbt2[4];
    #pragma unroll
    for (int nt = 0; nt < 4; ++nt){
      int col = w*64 + nt*16 + n16;
      rb1[nt] = p.b1[col]; rg1[nt] = p.g1[col]; rbt1[nt] = p.bt1[col];
      rb2[nt] = p.b2[col]; rg2[nt] = p.g2[col]; rbt2[nt] = p.bt2[col];
    }
    const int h0 = w*32 + n16, h1 = h0 + 16;

    float mu, sq;
    if (p.do_enc){
      if (tid < IND) sc1[tid] = p.path[(b*SS + 0)*IND + tid];
      __syncthreads();
      float acc = 0.f;
      if (tid < HID){
        acc = p.eb1[tid];
        #pragma unroll 8
        for (int i = 0; i < IND; ++i) acc = fmaf(sc1[i], p.eW1[i*HID + tid], acc);
      }
      float cx = (tid < HID) ? acc : 0.f;
      bsum2(cx, cx*cx, red, tid, mu, sq);
      mu *= (1.f/HID); float var = sq*(1.f/HID) - mu*mu; float rstd = rsqrtf(var + 1e-5f);
      if (tid < HID) zf[tid] = gelu_f((acc - mu)*rstd*p.eg1[tid] + p.ebt1[tid]);
      __syncthreads();
      float acc2 = 0.f;
      if (tid < HID){
        acc2 = p.eb2[tid];
        #pragma unroll 8
        for (int h = 0; h < HID; ++h) acc2 = fmaf(zf[h], p.eW2[h*HID + tid], acc2);
      }
      cx = (tid < HID) ? acc2 : 0.f;
      bsum2(cx, cx*cx, red, tid, mu, sq);
      mu *= (1.f/HID); float var2 = sq*(1.f/HID) - mu*mu; float rstd2 = rsqrtf(var2 + 1e-5f);
      __syncthreads();
      if (tid < HID) zf[tid] = (acc2 - mu)*rstd2*p.eg2[tid] + p.ebt2[tid];
      __syncthreads();
    }
    float zc0 = 0.f, zc1 = 0.f;
    if (owner){
      if (p.do_enc){ zc0 = zf[h0]; zc1 = zf[h1]; }
      else { zc0 = p.zstate[b*HID + h0]; zc1 = p.zstate[b*HID + h1]; }
    }

    for (int s = p.s0; s < p.s1; ++s){
      const float hbv = p.hb[b*NSTEP + s];
      uint4 gr[16];
      {
        const uint4* g4 = (const uint4*)(p.Gp + ((size_t)(s - p.s0)*BB + b)*16384 + (size_t)w*4096);
        #pragma unroll
        for (int m = 0; m < 16; ++m) gr[m] = g4[m*64 + lane];
      }
      float gb0 = 0.f, gb1 = 0.f;
      if (owner){
        gb0 = p.gb[(b*NSTEP + s)*HID + h0];
        gb1 = p.gb[(b*NSTEP + s)*HID + h1];
        zst_h[h0] = f2h(zc0); zst_h[h1] = f2h(zc1);
      }
      float ks0 = 0.f, ks1 = 0.f;
      __syncthreads();

      #pragma unroll 1
      for (int st = 0; st < 4; ++st){
        // layer1: zst(1x128) @ W1(128x256), 16 MFMA, 8 accumulators
        f32x4 D0a={0,0,0,0}, D1a={0,0,0,0}, D2a={0,0,0,0}, D3a={0,0,0,0};
        f32x4 D0b={0,0,0,0}, D1b={0,0,0,0}, D2b={0,0,0,0}, D3b={0,0,0,0};
        {
          const uint4* za = (const uint4*)zst_h;
          #pragma unroll
          for (int kt = 0; kt < 2; ++kt){
            f16x8 a; uint4 av = za[kt*4 + quad]; __builtin_memcpy(&a, &av, 16);
            f16x8 bf;
            __builtin_memcpy(&bf, &w1r[kt*4+0], 16); D0a = __builtin_amdgcn_mfma_f32_16x16x32_f16(a, bf, D0a, 0, 0, 0);
            __builtin_memcpy(&bf, &w1r[kt*4+1], 16); D1a = __builtin_amdgcn_mfma_f32_16x16x32_f16(a, bf, D1a, 0, 0, 0);
            __builtin_memcpy(&bf, &w1r[kt*4+2], 16); D2a = __builtin_amdgcn_mfma_f32_16x16x32_f16(a, bf, D2a, 0, 0, 0);
            __builtin_memcpy(&bf, &w1r[kt*4+3], 16); D3a = __builtin_amdgcn_mfma_f32_16x16x32_f16(a, bf, D3a, 0, 0, 0);
          }
          #pragma unroll
          for (int kt = 2; kt < 4; ++kt){
            f16x8 a; uint4 av = za[kt*4 + quad]; __builtin_memcpy(&a, &av, 16);
            f16x8 bf;
            __builtin_memcpy(&bf, &w1r[kt*4+0], 16); D0b = __builtin_amdgcn_mfma_f32_16x16x32_f16(a, bf, D0b, 0, 0, 0);
            __builtin_memcpy(&bf, &w1r[kt*4+1], 16); D1b = __builtin_amdgcn_mfma_f32_16x16x32_f16(a, bf, D1b, 0, 0, 0);
            __builtin_memcpy(&bf, &w1r[kt*4+2], 16); D2b = __builtin_amdgcn_mfma_f32_16x16x32_f16(a, bf, D2b, 0, 0, 0);
            __builtin_memcpy(&bf, &w1r[kt*4+3], 16); D3b = __builtin_amdgcn_mfma_f32_16x16x32_f16(a, bf, D3b, 0, 0, 0);
          }
        }
        float v0 = (D0a[0]+D0b[0]) + rb1[0], v1 = (D1a[0]+D1b[0]) + rb1[1];
        float v2 = (D2a[0]+D2b[0]) + rb1[2], v3 = (D3a[0]+D3b[0]) + rb1[3];
        float ssum = wred((v0 + v1) + (v2 + v3));
        float ssq  = wred((v0*v0 + v1*v1) + (v2*v2 + v3*v3));
        if (lane == 63){ red[w*2] = ssum; red[w*2+1] = ssq; }
        __syncthreads();                                    // b1
        {
          const float4* r4 = (const float4*)red;
          float4 ra = r4[0], rb = r4[1];
          float m1 = (ra.x + ra.z + rb.x + rb.z)*(1.f/1024.f);
          float q1 = (ra.y + ra.w + rb.y + rb.w)*(1.f/1024.f);
          float rs1 = rsqrtf(q1 - m1*m1 + 1e-5f);
          if (owner){
            a1p_h[w*64 +  0 + n16] = f2h(gelu_f((v0 - m1)*rs1*rg1[0] + rbt1[0]));
            a1p_h[w*64 + 16 + n16] = f2h(gelu_f((v1 - m1)*rs1*rg1[1] + rbt1[1]));
            a1p_h[w*64 + 32 + n16] = f2h(gelu_f((v2 - m1)*rs1*rg1[2] + rbt1[2]));
            a1p_h[w*64 + 48 + n16] = f2h(gelu_f((v3 - m1)*rs1*rg1[3] + rbt1[3]));
          }
        }
        __syncthreads();                                    // b2
        // layer2: a1(1x256) @ W2(256x256), 32 MFMA, 8 accumulators
        D0a={0,0,0,0}; D1a={0,0,0,0}; D2a={0,0,0,0}; D3a={0,0,0,0};
        D0b={0,0,0,0}; D1b={0,0,0,0}; D2b={0,0,0,0}; D3b={0,0,0,0};
        {
          const uint4* aa = (const uint4*)a1p_h;
          #pragma unroll
          for (int kt = 0; kt < 4; ++kt){
            f16x8 a; uint4 av = aa[kt*4 + quad]; __builtin_memcpy(&a, &av, 16);
            f16x8 bf;
            __builtin_memcpy(&bf, &w2r[kt*4+0], 16); D0a = __builtin_amdgcn_mfma_f32_16x16x32_f16(a, bf, D0a, 0, 0, 0);
            __builtin_memcpy(&bf, &w2r[kt*4+1], 16); D1a = __builtin_amdgcn_mfma_f32_16x16x32_f16(a, bf, D1a, 0, 0, 0);
            __builtin_memcpy(&bf, &w2r[kt*4+2], 16); D2a = __builtin_amdgcn_mfma_f32_16x16x32_f16(a, bf, D2a, 0, 0, 0);
            __builtin_memcpy(&bf, &w2r[kt*4+3], 16); D3a = __builtin_amdgcn_mfma_f32_16x16x32_f16(a, bf, D3a, 0, 0, 0);
          }
          #pragma unroll
          for (int kt = 4; kt < 8; ++kt){
            f16x8 a; uint4 av = aa[kt*4 + quad]; __builtin_memcpy(&a, &av, 16);
            f16x8 bf;
            __builtin_memcpy(&bf, &w2r[kt*4+0], 16); D0b = __builtin_amdgcn_mfma_f32_16x16x32_f16(a, bf, D0b, 0, 0, 0);
            __builtin_memcpy(&bf, &w2r[kt*4+1], 16); D1b = __builtin_amdgcn_mfma_f32_16x16x32_f16(a, bf, D1b, 0, 0, 0);
            __builtin_memcpy(&bf, &w2r[kt*4+2], 16); D2b = __builtin_amdgcn_mfma_f32_16x16x32_f16(a, bf, D2b, 0, 0, 0);
            __builtin_memcpy(&bf, &w2r[kt*4+3], 16); D3b = __builtin_amdgcn_mfma_f32_16x16x32_f16(a, bf, D3b, 0, 0, 0);
          }
        }
        v0 = (D0a[0]+D0b[0]) + rb2[0]; v1 = (D1a[0]+D1b[0]) + rb2[1];
        v2 = (D2a[0]+D2b[0]) + rb2[2]; v3 = (D3a[0]+D3b[0]) + rb2[3];
        ssum = wred((v0 + v1) + (v2 + v3));
        ssq  = wred((v0*v0 + v1*v1) + (v2*v2 + v3*v3));
        if (lane == 63){ red[w*2] = ssum; red[w*2+1] = ssq; }
        __syncthreads();                                    // b3
        {
          const float4* r4 = (const float4*)red;
          float4 ra = r4[0], rb = r4[1];
          float m2 = (ra.x + ra.z + rb.x + rb.z)*(1.f/1024.f);
          float q2 = (ra.y + ra.w + rb.y + rb.w)*(1.f/1024.f);
          float rs2 = rsqrtf(q2 - m2*m2 + 1e-5f);
          if (owner){
            a2p_h[w*64 +  0 + n16] = f2h(gelu_f((v0 - m2)*rs2*rg2[0] + rbt2[0]));
            a2p_h[w*64 + 16 + n16] = f2h(gelu_f((v1 - m2)*rs2*rg2[1] + rbt2[1]));
            a2p_h[w*64 + 32 + n16] = f2h(gelu_f((v2 - m2)*rs2*rg2[2] + rbt2[2]));
            a2p_h[w*64 + 48 + n16] = f2h(gelu_f((v3 - m2)*rs2*rg2[3] + rbt2[3]));
          }
        }
        __syncthreads();                                    // b4
        // layer3: a2(1x256) @ G(256x32 cols of this wave), 16 MFMA, 4 accumulators
        f32x4 E0={0,0,0,0}, E1={0,0,0,0}, E2={0,0,0,0}, E3={0,0,0,0};
        {
          const uint4* aa = (const uint4*)a2p_h;
          #pragma unroll
          for (int kt = 0; kt < 4; ++kt){
            f16x8 a; uint4 av = aa[kt*4 + quad]; __builtin_memcpy(&a, &av, 16);
            f16x8 g0f, g1f;
            __builtin_memcpy(&g0f, &gr[kt*2+0], 16);
            __builtin_memcpy(&g1f, &gr[kt*2+1], 16);
            E0 = __builtin_amdgcn_mfma_f32_16x16x32_f16(a, g0f, E0, 0, 0, 0);
            E1 = __builtin_amdgcn_mfma_f32_16x16x32_f16(a, g1f, E1, 0, 0, 0);
          }
          #pragma unroll
          for (int kt = 4; kt < 8; ++kt){
            f16x8 a; uint4 av = aa[kt*4 + quad]; __builtin_memcpy(&a, &av, 16);
            f16x8 g0f, g1f;
            __builtin_memcpy(&g0f, &gr[kt*2+0], 16);
            __builtin_memcpy(&g1f, &gr[kt*2+1], 16);
            E2 = __builtin_amdgcn_mfma_f32_16x16x32_f16(a, g0f, E2, 0, 0, 0);
            E3 = __builtin_amdgcn_mfma_f32_16x16x32_f16(a, g1f, E3, 0, 0, 0);
          }
        }
        if (owner){
          float kv0 = (E0[0] + E2[0]) + gb0, kv1 = (E1[0] + E3[0]) + gb1;
          float cst = (st == 0 || st == 3) ? 1.f : 2.f;
          ks0 += cst*kv0; ks1 += cst*kv1;
          if (st < 3){
            float c = (st == 2) ? hbv : 0.5f*hbv;
            zst_h[h0] = f2h(zc0 + c*kv0);
            zst_h[h1] = f2h(zc1 + c*kv1);
          }
        }
        __syncthreads();                                    // b5
      }
      if (owner){ zc0 += hbv*(1.f/6.f)*ks0; zc1 += hbv*(1.f/6.f)*ks1; }
    }

    if (p.do_epi){
      if (owner){ zf[h0] = zc0; zf[h1] = zc1; }
      __syncthreads();
      if (tid < HID){
        float v = p.bv[tid];
        #pragma unroll 8
        for (int h = 0; h < HID; ++h) v = fmaf(zf[h], p.Wv[h*HID + tid], v);
        sc1[tid] = v;
      }
      __syncthreads();
      if (tid < HID){
        float f = p.bo[tid];
        #pragma unroll 8
        for (int h = 0; h < HID; ++h) f = fmaf(sc1[h], p.Wo[h*HID + tid], f);
        sc1[HID + tid] = f;
      }
      __syncthreads();
      if (tid < HID){
        float hd = p.db1[tid];
        #pragma unroll 8
        for (int h = 0; h < HID; ++h) hd = fmaf(sc1[HID + h], p.dW1[h*HID + tid], hd);
        zf[tid] = gelu_f(hd);
      }
      __syncthreads();
      if (tid < 10){
        float t = p.db2[tid];
        #pragma unroll 8
        for (int h = 0; h < HID; ++h) t = fmaf(zf[h], p.dW2[h*10 + tid], t);
        p.out[b*10 + tid] = t;
      }
      if (tid == 0) p.out[BB*10 + b] = 1.0f;   // softmax over singleton axis == 1
    } else {
      if (owner){ p.zstate[b*HID + h0] = zc0; p.zstate[b*HID + h1] = zc1; }
    }
    return;
  }

  // ================= G-PREP (VALU dot2, 64 blocks/step — R10 verified) =================
  {
    setprio_lo();
    const int pb = blockIdx.x - (p.scan_on ? BB : 0);
    const int sl = pb >> 6, xblk = pb & 63;
    if (sl >= p.pcs) return;
    const int s = p.ps0 + sl;
    const int lin = xblk*256 + tid;              // (kp, h)
    const int kp = lin >> 7, h = lin & 127;
    const uint4* wa = (const uint4*)(p.w3h + ((size_t)(2*kp)*HID + h)*16);
    const uint4* wb = (const uint4*)(p.w3h + ((size_t)(2*kp+1)*HID + h)*16);
    uint4 A0 = wa[0], A1 = wa[1], A2 = wa[2], A3 = wa[3];
    uint4 B0 = wb[0], B1 = wb[1], B2 = wb[2], B3 = wb[3];
    for (int t = tid; t < BB * 16; t += 256){
      int bb = t >> 4, i2 = t & 15;
      sdx[t] = p.dxh[((size_t)bb*NSTEP + s)*16 + i2];
    }
    __syncthreads();
    // fragment-layout output offset
    const int kt = kp >> 4, q = kp & 3, quad2 = (kp >> 2) & 3;
    const int wq = h >> 5, tq = (h >> 4) & 1, nn = h & 15;
    const size_t off = (size_t)wq*4096 + (size_t)(kt*2 + tq)*256 + (size_t)(quad2*16 + nn)*4 + q;
    const size_t base_sl = (size_t)sl * BB * 16384;
    u32* __restrict__ Gout = p.Gpw;
    for (int bb = 0; bb < BB; ++bb){
      const uint4* dp = (const uint4*)&sdx[bb*16];
      uint4 D0 = dp[0], D1 = dp[1], D2 = dp[2], D3 = dp[3];
      float g0 = 0.f, g1 = 0.f, g2 = 0.f, g3 = 0.f;
      g0 = dot2f(D0.x, A0.x, g0); g0 = dot2f(D0.y, A0.y, g0);
      g0 = dot2f(D0.z, A0.z, g0); g0 = dot2f(D0.w, A0.w, g0);
      g2 = dot2f(D1.x, A1.x, g2); g2 = dot2f(D1.y, A1.y, g2);
      g2 = dot2f(D1.z, A1.z, g2); g2 = dot2f(D1.w, A1.w, g2);
      g0 = dot2f(D2.x, A2.x, g0); g0 = dot2f(D2.y, A2.y, g0);
      g0 = dot2f(D2.z, A2.z, g0); g0 = dot2f(D2.w, A2.w, g0);
      g2 = dot2f(D3.x, A3.x, g2); g2 = dot2f(D3.y, A3.y, g2);
      g2 = dot2f(D3.z, A3.z, g2); g2 = dot2f(D3.w, A3.w, g2);
      g1 = dot2f(D0.x, B0.x, g1); g1 = dot2f(D0.y, B0.y, g1);
      g1 = dot2f(D0.z, B0.z, g1); g1 = dot2f(D0.w, B0.w, g1);
      g3 = dot2f(D1.x, B1.x, g3); g3 = dot2f(D1.y, B1.y, g3);
      g3 = dot2f(D1.z, B1.z, g3); g3 = dot2f(D1.w, B1.w, g3);
      g1 = dot2f(D2.x, B2.x, g1); g1 = dot2f(D2.y, B2.y, g1);
      g1 = dot2f(D2.z, B2.z, g1); g1 = dot2f(D2.w, B2.w, g1);
      g3 = dot2f(D3.x, B3.x, g3); g3 = dot2f(D3.y, B3.y, g3);
      g3 = dot2f(D3.x, B3.x, g3) - dot2f(D3.x, B3.x, 0.f) + g3*0.f + (dot2f(D3.y, B3.y, dot2f(D3.z, B3.z, dot2f(D3.w, B3.w, g3))));
      Gout[base_sl + (size_t)bb*16384 + off] = pkh2(g0 + g2, g1 + g3);
    }
  }
}

extern "C" void kernel_launch(void* const* d_in, const int* in_sizes, int n_in,
                              void* d_out, int out_size, void* d_ws, size_t ws_size,
                              hipStream_t stream){
  const float* path  = (const float*)d_in[0];
  const float* ts    = (const float*)d_in[1];
  const float* eW1   = (const float*)d_in[2];
  const float* eb1   = (const float*)d_in[3];
  const float* eg1   = (const float*)d_in[4];
  const float* ebt1  = (const float*)d_in[5];
  const float* eW2   = (const float*)d_in[6];
  const float* eb2   = (const float*)d_in[7];
  const float* eg2   = (const float*)d_in[8];
  const float* ebt2  = (const float*)d_in[9];
  const float* vW1   = (const float*)d_in[10];
  const float* vb1   = (const float*)d_in[11];
  const float* vg1   = (const float*)d_in[12];
  const float* vbt1  = (const float*)d_in[13];
  const float* vW2   = (const float*)d_in[14];
  const float* vb2   = (const float*)d_in[15];
  const float* vg2   = (const float*)d_in[16];
  const float* vbt2  = (const float*)d_in[17];
  const float* vW3   = (const float*)d_in[18];
  const float* vb3   = (const float*)d_in[19];
  const float* Wv    = (const float*)d_in[24];
  const float* bv    = (const float*)d_in[25];
  const float* Wo    = (const float*)d_in[26];
  const float* bo    = (const float*)d_in[27];
  const float* dW1   = (const float*)d_in[28];
  const float* db1   = (const float*)d_in[29];
  const float* dW2   = (const float*)d_in[30];
  const float* db2   = (const float*)d_in[31];

  char* wsb = (char*)d_ws;
  float* z_state = (float*)(wsb + 0);              // 64 KB
  u32*   dxh = (u32*)(wsb + 65536);                // 248 KB
  float* hb  = (float*)(wsb + 319488);             // 16 KB
  float* gb  = (float*)(wsb + 335872);             // 1.94 MB
  u32*   w3h = (u32*)(wsb + 2367488);              // 2 MB
  u32*   w1f = (u32*)(wsb + 4464640);              // 64 KB
  u32*   w2f = (u32*)(wsb + 4530176);              // 128 KB
  const size_t gbase = 4661248;

  hipLaunchKernelGGL(setup_kernel, dim3(BB + 2048 + 192), dim3(256), 0, stream,
                     path, ts, vb3, vW3, vW1, vW2, dxh, hb, gb, w3h, w1f, w2f);

  const size_t per_step = (size_t)BB * 16384 * 4;  // 8 MB per step
  size_t avail = (ws_size > gbase) ? (ws_size - gbase) : 0;
  int cap = (int)((avail/2) / per_step);           // max chunk with double buffer

  FusedP base;
  base.path = path;
  base.eW1 = eW1; base.eb1 = eb1; base.eg1 = eg1; base.ebt1 = ebt1;
  base.eW2 = eW2; base.eb2 = eb2; base.eg2 = eg2; base.ebt2 = ebt2;
  base.w1f = w1f; base.w2f = w2f;
  base.b1 = vb1; base.g1 = vg1; base.bt1 = vbt1;
  base.b2 = vb2; base.g2 = vg2; base.bt2 = vbt2;
  base.Wv = Wv; base.bv = bv; base.Wo = Wo; base.bo = bo;
  base.dW1 = dW1; base.db1 = db1; base.dW2 = dW2; base.db2 = db2;
  base.hb = hb; base.gb = gb;
  base.zstate = z_state; base.out = (float*)d_out;
  base.w3h = w3h; base.dxh = dxh;
  base.s0 = 0; base.s1 = 0; base.do_enc = 0; base.do_epi = 0; base.scan_on = 0;
  base.ps0 = 0; base.pcs = 0;

  if (cap >= 9){
    // measured-rate schedule: prep chunks <=9, paired prep <= ~1.4x scan
    const int sched[4] = {6, 7, 9, 9};
    const int n = 4;
    int s_off[5]; s_off[0] = 0;
    for (int i = 0; i < n; ++i) s_off[i+1] = s_off[i] + sched[i];
    u32* GpA = (u32*)(wsb + gbase);
    u32* GpB = (u32*)(wsb + gbase + (size_t)9*per_step);
    for (int i = 0; i <= n; ++i){
      FusedP P = base;
      int scan_i = i - 1, prep_i = i;
      P.scan_on = (scan_i >= 0) ? 1 : 0;
      if (P.scan_on){
        P.s0 = s_off[scan_i];
        P.s1 = s_off[scan_i + 1];
        P.Gp = (scan_i & 1) ? GpB : GpA;
        P.do_enc = (scan_i == 0) ? 1 : 0;
        P.do_epi = (P.s1 == NSTEP) ? 1 : 0;
      } else {
        P.Gp = GpA;
      }
      if (prep_i < n){
        P.ps0 = s_off[prep_i];
        P.pcs = sched[prep_i];
        P.Gpw = (prep_i & 1) ? GpB : GpA;
      } else {
        P.pcs = 0; P.Gpw = GpA;
      }
      int grid = (P.scan_on ? BB : 0) + 64*P.pcs;
      if (grid == 0) continue;
      hipLaunchKernelGGL(fused_kernel, dim3(grid), dim3(256), 0, stream, P);
    }
  } else if (cap >= 2){
    int c = cap < 8 ? cap : 8;
    if (c > NSTEP) c = NSTEP;
    const int nch = (NSTEP + c - 1) / c;
    u32* GpA = (u32*)(wsb + gbase);
    u32* GpB = (u32*)(wsb + gbase + (size_t)c*per_step);
    for (int i = 0; i <= nch; ++i){
      FusedP P = base;
      int scan_i = i - 1, prep_i = i;
      P.scan_on = (scan_i >= 0) ? 1 : 0;
      if (P.scan_on){
        P.s0 = scan_i*c;
        P.s1 = (P.s0 + c < NSTEP) ? (P.s0 + c) : NSTEP;
        P.Gp = (scan_i & 1) ? GpB : GpA;
        P.do_enc = (scan_i == 0) ? 1 : 0;
        P.do_epi = (P.s1 == NSTEP) ? 1 : 0;
      } else {
        P.Gp = GpA;
      }
      if (prep_i < nch){
        P.ps0 = prep_i*c;
        P.pcs = (NSTEP - P.ps0 < c) ? (NSTEP - P.ps0) : c;
        P.Gpw = (prep_i & 1) ? GpB : GpA;
      } else {
        P.pcs = 0; P.Gpw = GpA;
      }
      int grid = (P.scan_on ? BB : 0) + 64*P.pcs;
      if (grid == 0) continue;
      hipLaunchKernelGGL(fused_kernel, dim3(grid), dim3(256), 0, stream, P);
    }
  } else {
    int c = (int)(avail / per_step);
    if (c < 1) c = 1;
    if (c > NSTEP) c = NSTEP;
    u32* GpA = (u32*)(wsb + gbase);
    const int nch = (NSTEP + c - 1) / c;
    for (int i = 0; i < nch; ++i){
      int s0 = i*c;
      int cs = (NSTEP - s0 < c) ? (NSTEP - s0) : c;
      FusedP P1 = base;                 // prep only
      P1.scan_on = 0; P1.ps0 = s0; P1.pcs = cs; P1.Gpw = GpA; P1.Gp = GpA;
      hipLaunchKernelGGL(fused_kernel, dim3(64*cs), dim3(256), 0, stream, P1);
      FusedP P2 = base;                 // scan only
      P2.scan_on = 1; P2.pcs = 0; P2.Gpw = GpA;
      P2.s0 = s0; P2.s1 = s0 + cs; P2.Gp = GpA;
      P2.do_enc = (s0 == 0) ? 1 : 0;
      P2.do_epi = (s0 + cs == NSTEP) ? 1 : 0;
      hipLaunchKernelGGL(fused_kernel, dim3(BB), dim3(256), 0, stream, P2);
    }
  }
}

// Round 14
// 525.010 us; speedup vs baseline: 1.1104x; 1.0458x over previous
//
#include <hip/hip_runtime.h>
#include <hip/hip_bf16.h>

#define BB 128
#define SS 32
#define NSTEP 31
#define IND 32
#define HID 128
#define HID2 256

typedef unsigned short u16;
typedef unsigned int u32;
typedef _Float16 f16;
typedef f16 h2 __attribute__((ext_vector_type(2)));
typedef __fp16 fp16v2 __attribute__((ext_vector_type(2)));
typedef _Float16 f16x8 __attribute__((ext_vector_type(8)));
typedef float f32x4 __attribute__((ext_vector_type(4)));

__device__ __forceinline__ float dot2f(u32 a, u32 b, float c){
#if __has_builtin(__builtin_amdgcn_fdot2)
  h2 ha, hb; __builtin_memcpy(&ha, &a, 4); __builtin_memcpy(&hb, &b, 4);
  return __builtin_amdgcn_fdot2(ha, hb, c, false);
#else
  h2 ha, hb; __builtin_memcpy(&ha, &a, 4); __builtin_memcpy(&hb, &b, 4);
  return c + (float)ha[0]*(float)hb[0] + (float)ha[1]*(float)hb[1];
#endif
}
__device__ __forceinline__ u32 pkh2(float a, float b){
  fp16v2 r = __builtin_amdgcn_cvt_pkrtz(a, b);
  u32 u; __builtin_memcpy(&u, &r, 4); return u;
}
__device__ __forceinline__ u16 f2h(float f){ f16 h = (f16)f; u16 u; __builtin_memcpy(&u, &h, 2); return u; }
__device__ __forceinline__ float gelu_f(float x){ return 0.5f * x * (1.0f + erff(x * 0.70710678118654752440f)); }
__device__ __forceinline__ void setprio_hi(){
#if __has_builtin(__builtin_amdgcn_s_setprio)
  __builtin_amdgcn_s_setprio(3);
#endif
}
__device__ __forceinline__ void setprio_lo(){
#if __has_builtin(__builtin_amdgcn_s_setprio)
  __builtin_amdgcn_s_setprio(0);
#endif
}

// DPP wave64 sum -> valid in lane 63
__device__ __forceinline__ float wred(float v){
  int iv; float tf;
  #define DPPADD(CTRL, RMASK) \
    __builtin_memcpy(&iv, &v, 4); \
    iv = __builtin_amdgcn_update_dpp(0, iv, CTRL, RMASK, 0xf, true); \
    __builtin_memcpy(&tf, &iv, 4); \
    v += tf;
  DPPADD(0x111, 0xf)
  DPPADD(0x112, 0xf)
  DPPADD(0x114, 0xf)
  DPPADD(0x118, 0xf)
  DPPADD(0x142, 0xa)
  DPPADD(0x143, 0xc)
  #undef DPPADD
  return v;
}

// block-wide sum of (x,y) over 256 threads — enc/epi only
__device__ __forceinline__ void bsum2(float x, float y, float* red, int tid, float& ox, float& oy){
  #pragma unroll
  for (int off = 32; off >= 1; off >>= 1){ x += __shfl_xor(x, off); y += __shfl_xor(y, off); }
  __syncthreads();
  if ((tid & 63) == 0){ red[(tid >> 6)*2] = x; red[(tid >> 6)*2 + 1] = y; }
  __syncthreads();
  ox = red[0] + red[2] + red[4] + red[6];
  oy = red[1] + red[3] + red[5] + red[7];
}

// ---------------- merged setup: prep_misc / pack_w3 / pack_wf ----------------
__global__ __launch_bounds__(256) void setup_kernel(const float* __restrict__ path,
                                                    const float* __restrict__ ts,
                                                    const float* __restrict__ b3,
                                                    const float* __restrict__ W3,
                                                    const float* __restrict__ W1,
                                                    const float* __restrict__ W2,
                                                    u32* __restrict__ dxh,
                                                    float* __restrict__ hb,
                                                    float* __restrict__ gb,
                                                    u32* __restrict__ w3h,
                                                    u32* __restrict__ w1f,
                                                    u32* __restrict__ w2f){
  const int blk = blockIdx.x, tid = threadIdx.x;
  if (blk < BB){
    // ---- prep_misc for batch b = blk ----
    const int b = blk;
    __shared__ float sdxp[NSTEP * IND];
    for (int t = tid; t < NSTEP * IND; t += 256){
      int s = t >> 5, i = t & 31;
      float dt = ts[b*SS + s + 1] - ts[b*SS + s];
      sdxp[t] = (path[(b*SS + s + 1)*IND + i] - path[(b*SS + s)*IND + i]) / dt;
    }
    if (tid < NSTEP) hb[b*NSTEP + tid] = ts[b*SS + tid + 1] - ts[b*SS + tid];
    __syncthreads();
    for (int t = tid; t < NSTEP * 16; t += 256){
      int s = t >> 4, i2 = t & 15;
      dxh[((size_t)b*NSTEP + s)*16 + i2] = pkh2(sdxp[s*IND + 2*i2], sdxp[s*IND + 2*i2 + 1]);
    }
    if (tid < HID){
      float w[IND];
      #pragma unroll
      for (int i = 0; i < IND; ++i) w[i] = b3[tid*IND + i];
      for (int s = 0; s < NSTEP; ++s){
        float a = 0.f;
        #pragma unroll
        for (int i = 0; i < IND; ++i) a = fmaf(w[i], sdxp[s*IND + i], a);
        gb[(b*NSTEP + s)*HID + tid] = a;
      }
    }
  } else if (blk < BB + 2048){
    int i = (blk - BB)*256 + tid;
    if (i < (HID2*HID*IND)/2) w3h[i] = pkh2(W3[2*i], W3[2*i + 1]);
  } else {
    int i = (blk - BB - 2048)*256 + tid;
    if (i < 16384){
      int lane_blk = i >> 6, rem = i & 63;
      int i16 = rem >> 2, q = rem & 3;
      int w = lane_blk >> 6, lane = lane_blk & 63;
      int kt = i16 >> 2, nt = i16 & 3;
      int k = kt*32 + (lane >> 4)*8 + 2*q;
      int col = w*64 + nt*16 + (lane & 15);
      w1f[i] = pkh2(W1[(size_t)k*HID2 + col], W1[(size_t)(k+1)*HID2 + col]);
    } else if (i < 16384 + 32768){
      int j = i - 16384;
      int lane_blk = j >> 7, rem = j & 127;
      int i32i = rem >> 2, q = rem & 3;
      int w = lane_blk >> 6, lane = lane_blk & 63;
      int kt = i32i >> 2, nt = i32i & 3;
      int k = kt*32 + (lane >> 4)*8 + 2*q;
      int col = w*64 + nt*16 + (lane & 15);
      w2f[j] = pkh2(W2[(size_t)k*HID2 + col], W2[(size_t)(k+1)*HID2 + col]);
    }
  }
}

// ---------------- fused scan + G-prep ----------------
struct FusedP {
  // scan
  const float *path;
  const float *eW1,*eb1,*eg1,*ebt1,*eW2,*eb2,*eg2,*ebt2;
  const u32 *w1f, *w2f;
  const float *b1,*g1,*bt1,*b2,*g2,*bt2;
  const float *Wv,*bv,*Wo,*bo,*dW1,*db1,*dW2,*db2;
  const float *hb,*gb;
  const u32 *Gp;          // scan-consumed buffer
  float *zstate, *out;
  int s0, s1, do_enc, do_epi, scan_on;
  // prep
  const u32 *w3h, *dxh;
  u32 *Gpw;               // prep-written buffer
  int ps0, pcs;
};

__global__ __launch_bounds__(256, 1) void fused_kernel(FusedP p){
  const int tid = threadIdx.x;
  // scan shared
  __shared__ __align__(16) u16 zst_h[HID];
  __shared__ __align__(16) u16 a1p_h[HID2];
  __shared__ __align__(16) u16 a2p_h[HID2];
  __shared__ __align__(16) float red[8];
  __shared__ __align__(16) float zf[HID];
  __shared__ __align__(16) float sc1[HID2];
  // prep shared
  __shared__ u32 sdx[BB * 16];

  if (p.scan_on && blockIdx.x < BB){
    // ================= SCAN =================
    setprio_hi();
    const int b = blockIdx.x;
    const int lane = tid & 63, w = tid >> 6;
    const int quad = lane >> 4, n16 = lane & 15;
    const bool owner = (quad == 0);

    uint4 w1r[16], w2r[32];
    {
      const uint4* s1p = (const uint4*)p.w1f + ((size_t)(w*64 + lane))*16;
      #pragma unroll
      for (int i = 0; i < 16; ++i) w1r[i] = s1p[i];
      const uint4* s2p = (const uint4*)p.w2f + ((size_t)(w*64 + lane))*32;
      #pragma unroll
      for (int i = 0; i < 32; ++i) w2r[i] = s2p[i];
    }
    float rb1[4], rg1[4], rbt1[4], rb2[4], rg2[4], rbt2[4];
    #pragma unroll
    for (int nt = 0; nt < 4; ++nt){
      int col = w*64 + nt*16 + n16;
      rb1[nt] = p.b1[col]; rg1[nt] = p.g1[col]; rbt1[nt] = p.bt1[col];
      rb2[nt] = p.b2[col]; rg2[nt] = p.g2[col]; rbt2[nt] = p.bt2[col];
    }
    const int h0 = w*32 + n16, h1 = h0 + 16;

    float mu, sq;
    if (p.do_enc){
      if (tid < IND) sc1[tid] = p.path[(b*SS + 0)*IND + tid];
      __syncthreads();
      float acc = 0.f;
      if (tid < HID){
        acc = p.eb1[tid];
        #pragma unroll 8
        for (int i = 0; i < IND; ++i) acc = fmaf(sc1[i], p.eW1[i*HID + tid], acc);
      }
      float cx = (tid < HID) ? acc : 0.f;
      bsum2(cx, cx*cx, red, tid, mu, sq);
      mu *= (1.f/HID); float var = sq*(1.f/HID) - mu*mu; float rstd = rsqrtf(var + 1e-5f);
      if (tid < HID) zf[tid] = gelu_f((acc - mu)*rstd*p.eg1[tid] + p.ebt1[tid]);
      __syncthreads();
      float acc2 = 0.f;
      if (tid < HID){
        acc2 = p.eb2[tid];
        #pragma unroll 8
        for (int h = 0; h < HID; ++h) acc2 = fmaf(zf[h], p.eW2[h*HID + tid], acc2);
      }
      cx = (tid < HID) ? acc2 : 0.f;
      bsum2(cx, cx*cx, red, tid, mu, sq);
      mu *= (1.f/HID); float var2 = sq*(1.f/HID) - mu*mu; float rstd2 = rsqrtf(var2 + 1e-5f);
      __syncthreads();
      if (tid < HID) zf[tid] = (acc2 - mu)*rstd2*p.eg2[tid] + p.ebt2[tid];
      __syncthreads();
    }
    float zc0 = 0.f, zc1 = 0.f;
    if (owner){
      if (p.do_enc){ zc0 = zf[h0]; zc1 = zf[h1]; }
      else { zc0 = p.zstate[b*HID + h0]; zc1 = p.zstate[b*HID + h1]; }
    }

    for (int s = p.s0; s < p.s1; ++s){
      const float hbv = p.hb[b*NSTEP + s];
      uint4 gr[16];
      {
        const uint4* g4 = (const uint4*)(p.Gp + ((size_t)(s - p.s0)*BB + b)*16384 + (size_t)w*4096);
        #pragma unroll
        for (int m = 0; m < 16; ++m) gr[m] = g4[m*64 + lane];
      }
      float gb0 = 0.f, gb1 = 0.f;
      if (owner){
        gb0 = p.gb[(b*NSTEP + s)*HID + h0];
        gb1 = p.gb[(b*NSTEP + s)*HID + h1];
        zst_h[h0] = f2h(zc0); zst_h[h1] = f2h(zc1);
      }
      float ks0 = 0.f, ks1 = 0.f;
      __syncthreads();

      #pragma unroll 1
      for (int st = 0; st < 4; ++st){
        // layer1: zst(1x128) @ W1(128x256), 16 MFMA, 8 accumulators
        f32x4 D0a={0,0,0,0}, D1a={0,0,0,0}, D2a={0,0,0,0}, D3a={0,0,0,0};
        f32x4 D0b={0,0,0,0}, D1b={0,0,0,0}, D2b={0,0,0,0}, D3b={0,0,0,0};
        {
          const uint4* za = (const uint4*)zst_h;
          #pragma unroll
          for (int kt = 0; kt < 2; ++kt){
            f16x8 a; uint4 av = za[kt*4 + quad]; __builtin_memcpy(&a, &av, 16);
            f16x8 bf;
            __builtin_memcpy(&bf, &w1r[kt*4+0], 16); D0a = __builtin_amdgcn_mfma_f32_16x16x32_f16(a, bf, D0a, 0, 0, 0);
            __builtin_memcpy(&bf, &w1r[kt*4+1], 16); D1a = __builtin_amdgcn_mfma_f32_16x16x32_f16(a, bf, D1a, 0, 0, 0);
            __builtin_memcpy(&bf, &w1r[kt*4+2], 16); D2a = __builtin_amdgcn_mfma_f32_16x16x32_f16(a, bf, D2a, 0, 0, 0);
            __builtin_memcpy(&bf, &w1r[kt*4+3], 16); D3a = __builtin_amdgcn_mfma_f32_16x16x32_f16(a, bf, D3a, 0, 0, 0);
          }
          #pragma unroll
          for (int kt = 2; kt < 4; ++kt){
            f16x8 a; uint4 av = za[kt*4 + quad]; __builtin_memcpy(&a, &av, 16);
            f16x8 bf;
            __builtin_memcpy(&bf, &w1r[kt*4+0], 16); D0b = __builtin_amdgcn_mfma_f32_16x16x32_f16(a, bf, D0b, 0, 0, 0);
            __builtin_memcpy(&bf, &w1r[kt*4+1], 16); D1b = __builtin_amdgcn_mfma_f32_16x16x32_f16(a, bf, D1b, 0, 0, 0);
            __builtin_memcpy(&bf, &w1r[kt*4+2], 16); D2b = __builtin_amdgcn_mfma_f32_16x16x32_f16(a, bf, D2b, 0, 0, 0);
            __builtin_memcpy(&bf, &w1r[kt*4+3], 16); D3b = __builtin_amdgcn_mfma_f32_16x16x32_f16(a, bf, D3b, 0, 0, 0);
          }
        }
        float v0 = (D0a[0]+D0b[0]) + rb1[0], v1 = (D1a[0]+D1b[0]) + rb1[1];
        float v2 = (D2a[0]+D2b[0]) + rb1[2], v3 = (D3a[0]+D3b[0]) + rb1[3];
        float ssum = wred((v0 + v1) + (v2 + v3));
        float ssq  = wred((v0*v0 + v1*v1) + (v2*v2 + v3*v3));
        if (lane == 63){ red[w*2] = ssum; red[w*2+1] = ssq; }
        __syncthreads();                                    // b1
        {
          const float4* r4 = (const float4*)red;
          float4 ra = r4[0], rb = r4[1];
          float m1 = (ra.x + ra.z + rb.x + rb.z)*(1.f/1024.f);
          float q1 = (ra.y + ra.w + rb.y + rb.w)*(1.f/1024.f);
          float rs1 = rsqrtf(q1 - m1*m1 + 1e-5f);
          if (owner){
            a1p_h[w*64 +  0 + n16] = f2h(gelu_f((v0 - m1)*rs1*rg1[0] + rbt1[0]));
            a1p_h[w*64 + 16 + n16] = f2h(gelu_f((v1 - m1)*rs1*rg1[1] + rbt1[1]));
            a1p_h[w*64 + 32 + n16] = f2h(gelu_f((v2 - m1)*rs1*rg1[2] + rbt1[2]));
            a1p_h[w*64 + 48 + n16] = f2h(gelu_f((v3 - m1)*rs1*rg1[3] + rbt1[3]));
          }
        }
        __syncthreads();                                    // b2
        // layer2: a1(1x256) @ W2(256x256), 32 MFMA, 8 accumulators
        D0a={0,0,0,0}; D1a={0,0,0,0}; D2a={0,0,0,0}; D3a={0,0,0,0};
        D0b={0,0,0,0}; D1b={0,0,0,0}; D2b={0,0,0,0}; D3b={0,0,0,0};
        {
          const uint4* aa = (const uint4*)a1p_h;
          #pragma unroll
          for (int kt = 0; kt < 4; ++kt){
            f16x8 a; uint4 av = aa[kt*4 + quad]; __builtin_memcpy(&a, &av, 16);
            f16x8 bf;
            __builtin_memcpy(&bf, &w2r[kt*4+0], 16); D0a = __builtin_amdgcn_mfma_f32_16x16x32_f16(a, bf, D0a, 0, 0, 0);
            __builtin_memcpy(&bf, &w2r[kt*4+1], 16); D1a = __builtin_amdgcn_mfma_f32_16x16x32_f16(a, bf, D1a, 0, 0, 0);
            __builtin_memcpy(&bf, &w2r[kt*4+2], 16); D2a = __builtin_amdgcn_mfma_f32_16x16x32_f16(a, bf, D2a, 0, 0, 0);
            __builtin_memcpy(&bf, &w2r[kt*4+3], 16); D3a = __builtin_amdgcn_mfma_f32_16x16x32_f16(a, bf, D3a, 0, 0, 0);
          }
          #pragma unroll
          for (int kt = 4; kt < 8; ++kt){
            f16x8 a; uint4 av = aa[kt*4 + quad]; __builtin_memcpy(&a, &av, 16);
            f16x8 bf;
            __builtin_memcpy(&bf, &w2r[kt*4+0], 16); D0b = __builtin_amdgcn_mfma_f32_16x16x32_f16(a, bf, D0b, 0, 0, 0);
            __builtin_memcpy(&bf, &w2r[kt*4+1], 16); D1b = __builtin_amdgcn_mfma_f32_16x16x32_f16(a, bf, D1b, 0, 0, 0);
            __builtin_memcpy(&bf, &w2r[kt*4+2], 16); D2b = __builtin_amdgcn_mfma_f32_16x16x32_f16(a, bf, D2b, 0, 0, 0);
            __builtin_memcpy(&bf, &w2r[kt*4+3], 16); D3b = __builtin_amdgcn_mfma_f32_16x16x32_f16(a, bf, D3b, 0, 0, 0);
          }
        }
        v0 = (D0a[0]+D0b[0]) + rb2[0]; v1 = (D1a[0]+D1b[0]) + rb2[1];
        v2 = (D2a[0]+D2b[0]) + rb2[2]; v3 = (D3a[0]+D3b[0]) + rb2[3];
        ssum = wred((v0 + v1) + (v2 + v3));
        ssq  = wred((v0*v0 + v1*v1) + (v2*v2 + v3*v3));
        if (lane == 63){ red[w*2] = ssum; red[w*2+1] = ssq; }
        __syncthreads();                                    // b3
        {
          const float4* r4 = (const float4*)red;
          float4 ra = r4[0], rb = r4[1];
          float m2 = (ra.x + ra.z + rb.x + rb.z)*(1.f/1024.f);
          float q2 = (ra.y + ra.w + rb.y + rb.w)*(1.f/1024.f);
          float rs2 = rsqrtf(q2 - m2*m2 + 1e-5f);
          if (owner){
            a2p_h[w*64 +  0 + n16] = f2h(gelu_f((v0 - m2)*rs2*rg2[0] + rbt2[0]));
            a2p_h[w*64 + 16 + n16] = f2h(gelu_f((v1 - m2)*rs2*rg2[1] + rbt2[1]));
            a2p_h[w*64 + 32 + n16] = f2h(gelu_f((v2 - m2)*rs2*rg2[2] + rbt2[2]));
            a2p_h[w*64 + 48 + n16] = f2h(gelu_f((v3 - m2)*rs2*rg2[3] + rbt2[3]));
          }
        }
        __syncthreads();                                    // b4
        // layer3: a2(1x256) @ G(256x32 cols of this wave), 16 MFMA, 4 accumulators
        f32x4 E0={0,0,0,0}, E1={0,0,0,0}, E2={0,0,0,0}, E3={0,0,0,0};
        {
          const uint4* aa = (const uint4*)a2p_h;
          #pragma unroll
          for (int kt = 0; kt < 4; ++kt){
            f16x8 a; uint4 av = aa[kt*4 + quad]; __builtin_memcpy(&a, &av, 16);
            f16x8 g0f, g1f;
            __builtin_memcpy(&g0f, &gr[kt*2+0], 16);
            __builtin_memcpy(&g1f, &gr[kt*2+1], 16);
            E0 = __builtin_amdgcn_mfma_f32_16x16x32_f16(a, g0f, E0, 0, 0, 0);
            E1 = __builtin_amdgcn_mfma_f32_16x16x32_f16(a, g1f, E1, 0, 0, 0);
          }
          #pragma unroll
          for (int kt = 4; kt < 8; ++kt){
            f16x8 a; uint4 av = aa[kt*4 + quad]; __builtin_memcpy(&a, &av, 16);
            f16x8 g0f, g1f;
            __builtin_memcpy(&g0f, &gr[kt*2+0], 16);
            __builtin_memcpy(&g1f, &gr[kt*2+1], 16);
            E2 = __builtin_amdgcn_mfma_f32_16x16x32_f16(a, g0f, E2, 0, 0, 0);
            E3 = __builtin_amdgcn_mfma_f32_16x16x32_f16(a, g1f, E3, 0, 0, 0);
          }
        }
        if (owner){
          float kv0 = (E0[0] + E2[0]) + gb0, kv1 = (E1[0] + E3[0]) + gb1;
          float cst = (st == 0 || st == 3) ? 1.f : 2.f;
          ks0 += cst*kv0; ks1 += cst*kv1;
          if (st < 3){
            float c = (st == 2) ? hbv : 0.5f*hbv;
            zst_h[h0] = f2h(zc0 + c*kv0);
            zst_h[h1] = f2h(zc1 + c*kv1);
          }
        }
        __syncthreads();                                    // b5
      }
      if (owner){ zc0 += hbv*(1.f/6.f)*ks0; zc1 += hbv*(1.f/6.f)*ks1; }
    }

    if (p.do_epi){
      if (owner){ zf[h0] = zc0; zf[h1] = zc1; }
      __syncthreads();
      if (tid < HID){
        float v = p.bv[tid];
        #pragma unroll 8
        for (int h = 0; h < HID; ++h) v = fmaf(zf[h], p.Wv[h*HID + tid], v);
        sc1[tid] = v;
      }
      __syncthreads();
      if (tid < HID){
        float f = p.bo[tid];
        #pragma unroll 8
        for (int h = 0; h < HID; ++h) f = fmaf(sc1[h], p.Wo[h*HID + tid], f);
        sc1[HID + tid] = f;
      }
      __syncthreads();
      if (tid < HID){
        float hd = p.db1[tid];
        #pragma unroll 8
        for (int h = 0; h < HID; ++h) hd = fmaf(sc1[HID + h], p.dW1[h*HID + tid], hd);
        zf[tid] = gelu_f(hd);
      }
      __syncthreads();
      if (tid < 10){
        float t = p.db2[tid];
        #pragma unroll 8
        for (int h = 0; h < HID; ++h) t = fmaf(zf[h], p.dW2[h*10 + tid], t);
        p.out[b*10 + tid] = t;
      }
      if (tid == 0) p.out[BB*10 + b] = 1.0f;   // softmax over singleton axis == 1
    } else {
      if (owner){ p.zstate[b*HID + h0] = zc0; p.zstate[b*HID + h1] = zc1; }
    }
    return;
  }

  // ================= G-PREP (low priority) =================
  {
    setprio_lo();
    const int pb = blockIdx.x - (p.scan_on ? BB : 0);
    const int sl = pb >> 6, xblk = pb & 63;
    if (sl >= p.pcs) return;
    const int s = p.ps0 + sl;
    const int lin = xblk*256 + tid;              // (kp, h)
    const int kp = lin >> 7, h = lin & 127;
    const uint4* wa = (const uint4*)(p.w3h + ((size_t)(2*kp)*HID + h)*16);
    const uint4* wb = (const uint4*)(p.w3h + ((size_t)(2*kp+1)*HID + h)*16);
    uint4 A0 = wa[0], A1 = wa[1], A2 = wa[2], A3 = wa[3];
    uint4 B0 = wb[0], B1 = wb[1], B2 = wb[2], B3 = wb[3];
    for (int t = tid; t < BB * 16; t += 256){
      int bb = t >> 4, i2 = t & 15;
      sdx[t] = p.dxh[((size_t)bb*NSTEP + s)*16 + i2];
    }
    __syncthreads();
    // fragment-layout output offset
    const int kt = kp >> 4, q = kp & 3, quad2 = (kp >> 2) & 3;
    const int wq = h >> 5, tq = (h >> 4) & 1, nn = h & 15;
    const size_t off = (size_t)wq*4096 + (size_t)(kt*2 + tq)*256 + (size_t)(quad2*16 + nn)*4 + q;
    const size_t base_sl = (size_t)sl * BB * 16384;
    u32* __restrict__ Gout = p.Gpw;
    for (int bb = 0; bb < BB; ++bb){
      const uint4* dp = (const uint4*)&sdx[bb*16];
      uint4 D0 = dp[0], D1 = dp[1], D2 = dp[2], D3 = dp[3];
      float g0 = 0.f, g1 = 0.f, g2 = 0.f, g3 = 0.f;
      g0 = dot2f(D0.x, A0.x, g0); g0 = dot2f(D0.y, A0.y, g0);
      g0 = dot2f(D0.z, A0.z, g0); g0 = dot2f(D0.w, A0.w, g0);
      g2 = dot2f(D1.x, A1.x, g2); g2 = dot2f(D1.y, A1.y, g2);
      g2 = dot2f(D1.z, A1.z, g2); g2 = dot2f(D1.w, A1.w, g2);
      g0 = dot2f(D2.x, A2.x, g0); g0 = dot2f(D2.y, A2.y, g0);
      g0 = dot2f(D2.z, A2.z, g0); g0 = dot2f(D2.w, A2.w, g0);
      g2 = dot2f(D3.x, A3.x, g2); g2 = dot2f(D3.y, A3.y, g2);
      g2 = dot2f(D3.z, A3.z, g2); g2 = dot2f(D3.w, A3.w, g2);
      g1 = dot2f(D0.x, B0.x, g1); g1 = dot2f(D0.y, B0.y, g1);
      g1 = dot2f(D0.z, B0.z, g1); g1 = dot2f(D0.w, B0.w, g1);
      g3 = dot2f(D1.x, B1.x, g3); g3 = dot2f(D1.y, B1.y, g3);
      g3 = dot2f(D1.z, B1.z, g3); g3 = dot2f(D1.w, B1.w, g3);
      g1 = dot2f(D2.x, B2.x, g1); g1 = dot2f(D2.y, B2.y, g1);
      g1 = dot2f(D2.z, B2.z, g1); g1 = dot2f(D2.w, B2.w, g1);
      g3 = dot2f(D3.x, B3.x, g3); g3 = dot2f(D3.y, B3.y, g3);
      g3 = dot2f(D3.z, B3.z, g3); g3 = dot2f(D3.w, B3.w, g3);
      Gout[base_sl + (size_t)bb*16384 + off] = pkh2(g0 + g2, g1 + g3);
    }
  }
}

extern "C" void kernel_launch(void* const* d_in, const int* in_sizes, int n_in,
                              void* d_out, int out_size, void* d_ws, size_t ws_size,
                              hipStream_t stream){
  const float* path  = (const float*)d_in[0];
  const float* ts    = (const float*)d_in[1];
  const float* eW1   = (const float*)d_in[2];
  const float* eb1   = (const float*)d_in[3];
  const float* eg1   = (const float*)d_in[4];
  const float* ebt1  = (const float*)d_in[5];
  const float* eW2   = (const float*)d_in[6];
  const float* eb2   = (const float*)d_in[7];
  const float* eg2   = (const float*)d_in[8];
  const float* ebt2  = (const float*)d_in[9];
  const float* vW1   = (const float*)d_in[10];
  const float* vb1   = (const float*)d_in[11];
  const float* vg1   = (const float*)d_in[12];
  const float* vbt1  = (const float*)d_in[13];
  const float* vW2   = (const float*)d_in[14];
  const float* vb2   = (const float*)d_in[15];
  const float* vg2   = (const float*)d_in[16];
  const float* vbt2  = (const float*)d_in[17];
  const float* vW3   = (const float*)d_in[18];
  const float* vb3   = (const float*)d_in[19];
  const float* Wv    = (const float*)d_in[24];
  const float* bv    = (const float*)d_in[25];
  const float* Wo    = (const float*)d_in[26];
  const float* bo    = (const float*)d_in[27];
  const float* dW1   = (const float*)d_in[28];
  const float* db1   = (const float*)d_in[29];
  const float* dW2   = (const float*)d_in[30];
  const float* db2   = (const float*)d_in[31];

  char* wsb = (char*)d_ws;
  float* z_state = (float*)(wsb + 0);              // 64 KB
  u32*   dxh = (u32*)(wsb + 65536);                // 248 KB
  float* hb  = (float*)(wsb + 319488);             // 16 KB
  float* gb  = (float*)(wsb + 335872);             // 1.94 MB
  u32*   w3h = (u32*)(wsb + 2367488);              // 2 MB
  u32*   w1f = (u32*)(wsb + 4464640);              // 64 KB
  u32*   w2f = (u32*)(wsb + 4530176);              // 128 KB
  const size_t gbase = 4661248;

  hipLaunchKernelGGL(setup_kernel, dim3(BB + 2048 + 192), dim3(256), 0, stream,
                     path, ts, vb3, vW3, vW1, vW2, dxh, hb, gb, w3h, w1f, w2f);

  const size_t per_step = (size_t)BB * 16384 * 4;  // 8 MB per step
  size_t avail = (ws_size > gbase) ? (ws_size - gbase) : 0;
  int cap = (int)((avail/2) / per_step);           // max chunk with double buffer

  FusedP base;
  base.path = path;
  base.eW1 = eW1; base.eb1 = eb1; base.eg1 = eg1; base.ebt1 = ebt1;
  base.eW2 = eW2; base.eb2 = eb2; base.eg2 = eg2; base.ebt2 = ebt2;
  base.w1f = w1f; base.w2f = w2f;
  base.b1 = vb1; base.g1 = vg1; base.bt1 = vbt1;
  base.b2 = vb2; base.g2 = vg2; base.bt2 = vbt2;
  base.Wv = Wv; base.bv = bv; base.Wo = Wo; base.bo = bo;
  base.dW1 = dW1; base.db1 = db1; base.dW2 = dW2; base.db2 = db2;
  base.hb = hb; base.gb = gb;
  base.zstate = z_state; base.out = (float*)d_out;
  base.w3h = w3h; base.dxh = dxh;
  base.s0 = 0; base.s1 = 0; base.do_enc = 0; base.do_epi = 0; base.scan_on = 0;
  base.ps0 = 0; base.pcs = 0;

  if (cap >= 2){
    int c = cap < 8 ? cap : 8;
    if (c > NSTEP) c = NSTEP;
    const int nch = (NSTEP + c - 1) / c;
    u32* GpA = (u32*)(wsb + gbase);
    u32* GpB = (u32*)(wsb + gbase + (size_t)c*per_step);
    for (int i = 0; i <= nch; ++i){
      FusedP P = base;
      int scan_i = i - 1, prep_i = i;
      P.scan_on = (scan_i >= 0) ? 1 : 0;
      if (P.scan_on){
        P.s0 = scan_i*c;
        P.s1 = (P.s0 + c < NSTEP) ? (P.s0 + c) : NSTEP;
        P.Gp = (scan_i & 1) ? GpB : GpA;
        P.do_enc = (scan_i == 0) ? 1 : 0;
        P.do_epi = (P.s1 == NSTEP) ? 1 : 0;
      } else {
        P.Gp = GpA;
      }
      if (prep_i < nch){
        P.ps0 = prep_i*c;
        P.pcs = (NSTEP - P.ps0 < c) ? (NSTEP - P.ps0) : c;
        P.Gpw = (prep_i & 1) ? GpB : GpA;
      } else {
        P.pcs = 0; P.Gpw = GpA;
      }
      int grid = (P.scan_on ? BB : 0) + 64*P.pcs;
      if (grid == 0) continue;
      hipLaunchKernelGGL(fused_kernel, dim3(grid), dim3(256), 0, stream, P);
    }
  } else {
    int c = (int)(avail / per_step);
    if (c < 1) c = 1;
    if (c > NSTEP) c = NSTEP;
    u32* GpA = (u32*)(wsb + gbase);
    const int nch = (NSTEP + c - 1) / c;
    for (int i = 0; i < nch; ++i){
      int s0 = i*c;
      int cs = (NSTEP - s0 < c) ? (NSTEP - s0) : c;
      FusedP P1 = base;                 // prep only
      P1.scan_on = 0; P1.ps0 = s0; P1.pcs = cs; P1.Gpw = GpA; P1.Gp = GpA;
      hipLaunchKernelGGL(fused_kernel, dim3(64*cs), dim3(256), 0, stream, P1);
      FusedP P2 = base;                 // scan only
      P2.scan_on = 1; P2.pcs = 0; P2.Gpw = GpA;
      P2.s0 = s0; P2.s1 = s0 + cs; P2.Gp = GpA;
      P2.do_enc = (s0 == 0) ? 1 : 0;
      P2.do_epi = (s0 + cs == NSTEP) ? 1 : 0;
      hipLaunchKernelGGL(fused_kernel, dim3(BB), dim3(256), 0, stream, P2);
    }
  }
}